// Round 1
// baseline (444.721 us; speedup 1.0000x reference)
//
#include <hip/hip_runtime.h>
#include <math.h>

// Problem constants (from reference)
#define NN 20000          // nodes
#define TT 4              // time steps
#define EE 320000         // edges
#define NT (NN*TT)        // 80000 rows
#define H1 8              // heads layer 1
#define F1 16             // feat per head layer 1
#define C1 (H1*F1)        // 128
#define IN_F 32
#define OUT_F 16

// ---------------------------------------------------------------------------
// Pass A: feat1 = x @ W1  [NT,128]; el1/er1 = head-dots  [NT,8]
// Block: 256 threads = 2 rows x 128 cols. W1 (16KB) + x rows staged in LDS.
// ---------------------------------------------------------------------------
__global__ __launch_bounds__(256) void k_feat1(
    const float* __restrict__ x, const float* __restrict__ W1,
    const float* __restrict__ al1, const float* __restrict__ ar1,
    float* __restrict__ feat1, float* __restrict__ el1, float* __restrict__ er1) {
  __shared__ float Ws[IN_F * C1];     // 4096 floats
  __shared__ float xs[2][IN_F];
  int tid = threadIdx.x;
#pragma unroll
  for (int i = 0; i < 16; ++i) Ws[tid + 256 * i] = W1[tid + 256 * i];
  int r = tid >> 7;                   // 0..1 (row within block)
  int col = tid & 127;
  int row = blockIdx.x * 2 + r;
  if (tid < 64) {
    int rr = tid >> 5, kk = tid & 31;
    xs[rr][kk] = x[(blockIdx.x * 2 + rr) * IN_F + kk];
  }
  __syncthreads();
  float acc = 0.f;
#pragma unroll
  for (int k = 0; k < IN_F; ++k) acc = fmaf(xs[r][k], Ws[k * C1 + col], acc);
  feat1[row * C1 + col] = acc;
  // 16-lane reduction for el/er (lanes of one head are contiguous)
  float ev = acc * al1[col];
  float rv = acc * ar1[col];
#pragma unroll
  for (int m = 8; m >= 1; m >>= 1) {
    ev += __shfl_xor(ev, m);
    rv += __shfl_xor(rv, m);
  }
  if ((col & 15) == 0) {
    int hh = col >> 4;
    el1[row * H1 + hh] = ev;
    er1[row * H1 + hh] = rv;
  }
}

// ---------------------------------------------------------------------------
// CSR build: counts -> exclusive scan -> scatter (sorted-by-dst src list)
// ---------------------------------------------------------------------------
__global__ void k_count(const int* __restrict__ dst, int* __restrict__ counts) {
  int e = blockIdx.x * 256 + threadIdx.x;
  if (e < EE) atomicAdd(&counts[dst[e]], 1);
}

__global__ __launch_bounds__(256) void k_scan(
    const int* __restrict__ counts, int* __restrict__ offs,
    int* __restrict__ cursor) {
  __shared__ int tmp[256];
  __shared__ int carry_s;
  int tid = threadIdx.x;
  if (tid == 0) carry_s = 0;
  __syncthreads();
  for (int base = 0; base < NN; base += 256) {
    int i = base + tid;
    int v = (i < NN) ? counts[i] : 0;
    tmp[tid] = v;
    __syncthreads();
    int run = v;
#pragma unroll
    for (int off = 1; off < 256; off <<= 1) {
      int add = (tid >= off) ? tmp[tid - off] : 0;
      __syncthreads();
      run += add;
      tmp[tid] = run;
      __syncthreads();
    }
    int excl = run - v;
    int carry = carry_s;
    if (i < NN) {
      offs[i] = carry + excl;
      cursor[i] = carry + excl;
    }
    __syncthreads();
    if (tid == 255) carry_s = carry + run;
    __syncthreads();
  }
  if (tid == 0) offs[NN] = carry_s;   // == EE
}

__global__ void k_scatter(const int* __restrict__ src, const int* __restrict__ dst,
                          int* __restrict__ cursor, int* __restrict__ csr_src) {
  int e = blockIdx.x * 256 + threadIdx.x;
  if (e < EE) {
    int d = dst[e];
    int pos = atomicAdd(&cursor[d], 1);
    csr_src[pos] = src[e];
  }
}

// ---------------------------------------------------------------------------
// Pass C: layer-1 softmax-aggregate. One block per dst node; 512 threads =
// (t,h,f) = (4,8,16). Single pass: l = sum exp(e), acc = sum exp(e)*feat.
// (e values are O(1): no max-shift needed, exp cannot overflow.)
// ---------------------------------------------------------------------------
__global__ __launch_bounds__(512) void k_agg1(
    const float* __restrict__ feat1, const float* __restrict__ el1,
    const float* __restrict__ er1, const int* __restrict__ offs,
    const int* __restrict__ csr_src, const float* __restrict__ b1,
    float* __restrict__ h) {
  int n = blockIdx.x;
  int tid = threadIdx.x;
  int t = tid >> 7, c = tid & 127, hh = c >> 4;
  int beg = offs[n], end = offs[n + 1];
  float ern = er1[(n * TT + t) * H1 + hh];
  float l = 0.f, acc = 0.f;
  for (int i = beg; i < end; ++i) {
    int s = csr_src[i];
    float e = el1[(s * TT + t) * H1 + hh] + ern;
    e = (e >= 0.f) ? e : 0.2f * e;
    float p = __expf(e);
    l += p;
    acc = fmaf(p, feat1[(s * TT + t) * C1 + c], acc);
  }
  float r = (l > 0.f) ? (acc / l) : 0.f;
  h[(n * TT + t) * C1 + c] = r + b1[c];
}

// ---------------------------------------------------------------------------
// Pass D: feat2 = h @ W2 [NT,16]; el2/er2 [NT]
// Block: 256 threads = 16 rows x 16 cols. W2 + h-tile staged in LDS (padded).
// ---------------------------------------------------------------------------
__global__ __launch_bounds__(256) void k_feat2(
    const float* __restrict__ h, const float* __restrict__ W2,
    const float* __restrict__ al2, const float* __restrict__ ar2,
    float* __restrict__ feat2, float* __restrict__ el2, float* __restrict__ er2) {
  __shared__ float Ws[C1 * OUT_F];    // 2048 floats
  __shared__ float hs[16 * 132];      // padded stride 132 -> no bank conflict
  int tid = threadIdx.x;
#pragma unroll
  for (int i = 0; i < 8; ++i) Ws[tid + 256 * i] = W2[tid + 256 * i];
  int base = blockIdx.x * 16;
#pragma unroll
  for (int i = 0; i < 8; ++i) {
    int j = tid + 256 * i;            // 0..2047
    int rr = j >> 7, kk = j & 127;
    hs[rr * 132 + kk] = h[(base + rr) * C1 + kk];
  }
  __syncthreads();
  int r = tid >> 4, col = tid & 15;
  float acc = 0.f;
#pragma unroll
  for (int k = 0; k < C1; ++k) acc = fmaf(hs[r * 132 + k], Ws[k * OUT_F + col], acc);
  int row = base + r;
  feat2[row * OUT_F + col] = acc;
  float ev = acc * al2[col];
  float rv = acc * ar2[col];
#pragma unroll
  for (int m = 8; m >= 1; m >>= 1) {
    ev += __shfl_xor(ev, m);
    rv += __shfl_xor(rv, m);
  }
  if (col == 0) {
    el2[row] = ev;
    er2[row] = rv;
  }
}

// ---------------------------------------------------------------------------
// Pass E: layer-2 softmax-aggregate. 4 nodes per 256-thread block; 64 threads
// per node = (t,f) = (4,16).
// ---------------------------------------------------------------------------
__global__ __launch_bounds__(256) void k_agg2(
    const float* __restrict__ feat2, const float* __restrict__ el2,
    const float* __restrict__ er2, const int* __restrict__ offs,
    const int* __restrict__ csr_src, const float* __restrict__ b2,
    float* __restrict__ out) {
  int tid = threadIdx.x;
  int n = blockIdx.x * 4 + (tid >> 6);
  int sub = tid & 63, t = sub >> 4, f = sub & 15;
  int beg = offs[n], end = offs[n + 1];
  float ern = er2[n * TT + t];
  float l = 0.f, acc = 0.f;
  for (int i = beg; i < end; ++i) {
    int s = csr_src[i];
    float e = el2[s * TT + t] + ern;
    e = (e >= 0.f) ? e : 0.2f * e;
    float p = __expf(e);
    l += p;
    acc = fmaf(p, feat2[(s * TT + t) * OUT_F + f], acc);
  }
  float r = (l > 0.f) ? (acc / l) : 0.f;
  out[(n * TT + t) * OUT_F + f] = r + b2[f];
}

// ---------------------------------------------------------------------------
extern "C" void kernel_launch(void* const* d_in, const int* in_sizes, int n_in,
                              void* d_out, int out_size, void* d_ws, size_t ws_size,
                              hipStream_t stream) {
  const float* x   = (const float*)d_in[0];
  const int*   src = (const int*)d_in[1];
  const int*   dst = (const int*)d_in[2];
  const float* W1  = (const float*)d_in[3];
  const float* al1 = (const float*)d_in[4];
  const float* ar1 = (const float*)d_in[5];
  const float* b1  = (const float*)d_in[6];
  const float* W2  = (const float*)d_in[7];
  const float* al2 = (const float*)d_in[8];
  const float* ar2 = (const float*)d_in[9];
  const float* b2  = (const float*)d_in[10];
  float* out = (float*)d_out;

  // Workspace layout (floats), ~95 MB total
  float* ws    = (float*)d_ws;
  float* feat1 = ws;                     // NT*128 = 10,240,000
  float* el1   = feat1 + (size_t)NT * C1;      // NT*8
  float* er1   = el1 + (size_t)NT * H1;        // NT*8
  float* h     = er1 + (size_t)NT * H1;        // NT*128
  float* feat2 = h + (size_t)NT * C1;          // NT*16
  float* el2   = feat2 + (size_t)NT * OUT_F;   // NT
  float* er2   = el2 + NT;                     // NT
  int* counts  = (int*)(er2 + NT);             // NN
  int* offs    = counts + NN;                  // NN+1 (pad to NN+4)
  int* cursor  = offs + NN + 4;                // NN
  int* csr_src = cursor + NN;                  // EE

  hipMemsetAsync(counts, 0, NN * sizeof(int), stream);

  k_feat1<<<NT / 2, 256, 0, stream>>>(x, W1, al1, ar1, feat1, el1, er1);
  k_count<<<EE / 256, 256, 0, stream>>>(dst, counts);
  k_scan<<<1, 256, 0, stream>>>(counts, offs, cursor);
  k_scatter<<<EE / 256, 256, 0, stream>>>(src, dst, cursor, csr_src);
  k_agg1<<<NN, 512, 0, stream>>>(feat1, el1, er1, offs, csr_src, b1, h);
  k_feat2<<<NT / 16, 256, 0, stream>>>(h, W2, al2, ar2, feat2, el2, er2);
  k_agg2<<<NN / 4, 256, 0, stream>>>(feat2, el2, er2, offs, csr_src, b2, out);
}

// Round 2
// 365.083 us; speedup vs baseline: 1.2181x; 1.2181x over previous
//
#include <hip/hip_runtime.h>
#include <math.h>

// Problem constants (from reference)
#define NN 20000          // nodes
#define TT 4              // time steps
#define EE 320000         // edges
#define NT (NN*TT)        // 80000 rows
#define H1 8              // heads layer 1
#define F1 16             // feat per head layer 1
#define C1 (H1*F1)        // 128
#define IN_F 32
#define OUT_F 16

// ---------------------------------------------------------------------------
// Pass A: feat1 = x @ W1  [NT,128]; el1/er1 = head-dots  [NT,8]
// Block: 256 threads, 16 rows per block (each thread: 8 rows x 1 col).
// W1 (16KB) staged once per 16 rows (was per 2 rows -> 8x less L2 traffic).
// ---------------------------------------------------------------------------
__global__ __launch_bounds__(256) void k_feat1(
    const float* __restrict__ x, const float* __restrict__ W1,
    const float* __restrict__ al1, const float* __restrict__ ar1,
    float* __restrict__ feat1, float* __restrict__ el1, float* __restrict__ er1) {
  __shared__ float Ws[IN_F * C1];     // 4096 floats
  __shared__ float xs[16][IN_F + 1];  // padded
  int tid = threadIdx.x;
#pragma unroll
  for (int i = 0; i < 16; ++i) Ws[tid + 256 * i] = W1[tid + 256 * i];
  int base = blockIdx.x * 16;
#pragma unroll
  for (int i = 0; i < 2; ++i) {
    int j = tid + 256 * i;            // 0..511
    int rr = j >> 5, kk = j & 31;
    xs[rr][kk] = x[(base + rr) * IN_F + kk];
  }
  __syncthreads();
  int col = tid & 127;
  int rhalf = tid >> 7;               // 0..1
  float acc[8];
#pragma unroll
  for (int q = 0; q < 8; ++q) acc[q] = 0.f;
#pragma unroll
  for (int k = 0; k < IN_F; ++k) {
    float w = Ws[k * C1 + col];
#pragma unroll
    for (int q = 0; q < 8; ++q) acc[q] = fmaf(xs[q * 2 + rhalf][k], w, acc[q]);
  }
  float alv = al1[col], arv = ar1[col];
  int hh = col >> 4;
#pragma unroll
  for (int q = 0; q < 8; ++q) {
    int row = base + q * 2 + rhalf;
    feat1[row * C1 + col] = acc[q];
    float ev = acc[q] * alv;
    float rv = acc[q] * arv;
#pragma unroll
    for (int m = 8; m >= 1; m >>= 1) {
      ev += __shfl_xor(ev, m);
      rv += __shfl_xor(rv, m);
    }
    if ((col & 15) == 0) {
      el1[row * H1 + hh] = ev;
      er1[row * H1 + hh] = rv;
    }
  }
}

// ---------------------------------------------------------------------------
// CSR build: counts -> exclusive scan -> scatter (sorted-by-dst src list)
// ---------------------------------------------------------------------------
__global__ void k_count(const int* __restrict__ dst, int* __restrict__ counts) {
  int e = blockIdx.x * 256 + threadIdx.x;
  if (e < EE) atomicAdd(&counts[dst[e]], 1);
}

// Single block, 1024 threads x 20 serial elements + one 1024-wide LDS scan.
__global__ __launch_bounds__(1024) void k_scan(
    const int* __restrict__ counts, int* __restrict__ offs,
    int* __restrict__ cursor) {
  __shared__ int sums[1024];
  int tid = threadIdx.x;
  int base = tid * 20;
  int local[20];
  int run = 0;
#pragma unroll
  for (int j = 0; j < 20; ++j) {
    int i = base + j;
    int v = (i < NN) ? counts[i] : 0;
    local[j] = run;                   // exclusive prefix within thread
    run += v;
  }
  sums[tid] = run;
  __syncthreads();
  int val = run;
#pragma unroll
  for (int off = 1; off < 1024; off <<= 1) {
    int add = (tid >= off) ? sums[tid - off] : 0;
    __syncthreads();
    val += add;
    sums[tid] = val;
    __syncthreads();
  }
  int excl = val - run;               // exclusive prefix at thread base
#pragma unroll
  for (int j = 0; j < 20; ++j) {
    int i = base + j;
    if (i < NN) {
      int o = excl + local[j];
      offs[i] = o;
      cursor[i] = o;
    }
  }
  if (tid == 1023) offs[NN] = val;    // == EE
}

__global__ void k_scatter(const int* __restrict__ src, const int* __restrict__ dst,
                          int* __restrict__ cursor, int* __restrict__ csr_src) {
  int e = blockIdx.x * 256 + threadIdx.x;
  if (e < EE) {
    int d = dst[e];
    int pos = atomicAdd(&cursor[d], 1);
    csr_src[pos] = src[e];
  }
}

// ---------------------------------------------------------------------------
// Pass C: layer-1 softmax-aggregate. One block per dst node; 512 threads =
// (t,h,f) = (4,8,16). Edge srcs staged wave-wide (lane-parallel load +
// __shfl broadcast) so the per-edge chain is just the feat/el gather; 2x
// unroll keeps 4 gathers in flight.
// ---------------------------------------------------------------------------
__global__ __launch_bounds__(512) void k_agg1(
    const float* __restrict__ feat1, const float* __restrict__ el1,
    const float* __restrict__ er1, const int* __restrict__ offs,
    const int* __restrict__ csr_src, const float* __restrict__ b1,
    float* __restrict__ h) {
  int n = blockIdx.x;
  int tid = threadIdx.x;
  int t = tid >> 7, c = tid & 127, hh = c >> 4;
  int lane = tid & 63;
  int beg = offs[n], end = offs[n + 1];
  float ern = er1[(n * TT + t) * H1 + hh];
  float l = 0.f, acc = 0.f;
  for (int chunk = beg; chunk < end; chunk += 64) {
    int m = min(64, end - chunk);
    int sv = (lane < m) ? csr_src[chunk + lane] : 0;
    int j = 0;
    for (; j + 2 <= m; j += 2) {
      int s0 = __shfl(sv, j);
      int s1 = __shfl(sv, j + 1);
      float e0 = el1[(s0 * TT + t) * H1 + hh];
      float e1 = el1[(s1 * TT + t) * H1 + hh];
      float f0 = feat1[(s0 * TT + t) * C1 + c];
      float f1 = feat1[(s1 * TT + t) * C1 + c];
      e0 += ern; e0 = (e0 >= 0.f) ? e0 : 0.2f * e0;
      e1 += ern; e1 = (e1 >= 0.f) ? e1 : 0.2f * e1;
      float p0 = __expf(e0);
      float p1 = __expf(e1);
      l += p0 + p1;
      acc = fmaf(p0, f0, acc);
      acc = fmaf(p1, f1, acc);
    }
    if (j < m) {
      int s0 = __shfl(sv, j);
      float e0 = el1[(s0 * TT + t) * H1 + hh] + ern;
      e0 = (e0 >= 0.f) ? e0 : 0.2f * e0;
      float p0 = __expf(e0);
      l += p0;
      acc = fmaf(p0, feat1[(s0 * TT + t) * C1 + c], acc);
    }
  }
  float r = (l > 0.f) ? (acc / l) : 0.f;
  h[(n * TT + t) * C1 + c] = r + b1[c];
}

// ---------------------------------------------------------------------------
// Pass D: feat2 = h @ W2 [NT,16]; el2/er2 [NT]
// ---------------------------------------------------------------------------
__global__ __launch_bounds__(256) void k_feat2(
    const float* __restrict__ h, const float* __restrict__ W2,
    const float* __restrict__ al2, const float* __restrict__ ar2,
    float* __restrict__ feat2, float* __restrict__ el2, float* __restrict__ er2) {
  __shared__ float Ws[C1 * OUT_F];    // 2048 floats
  __shared__ float hs[16 * 132];      // padded stride
  int tid = threadIdx.x;
#pragma unroll
  for (int i = 0; i < 8; ++i) Ws[tid + 256 * i] = W2[tid + 256 * i];
  int base = blockIdx.x * 16;
#pragma unroll
  for (int i = 0; i < 8; ++i) {
    int j = tid + 256 * i;            // 0..2047
    int rr = j >> 7, kk = j & 127;
    hs[rr * 132 + kk] = h[(base + rr) * C1 + kk];
  }
  __syncthreads();
  int r = tid >> 4, col = tid & 15;
  float acc = 0.f;
#pragma unroll
  for (int k = 0; k < C1; ++k) acc = fmaf(hs[r * 132 + k], Ws[k * OUT_F + col], acc);
  int row = base + r;
  feat2[row * OUT_F + col] = acc;
  float ev = acc * al2[col];
  float rv = acc * ar2[col];
#pragma unroll
  for (int m = 8; m >= 1; m >>= 1) {
    ev += __shfl_xor(ev, m);
    rv += __shfl_xor(rv, m);
  }
  if (col == 0) {
    el2[row] = ev;
    er2[row] = rv;
  }
}

// ---------------------------------------------------------------------------
// Pass E: layer-2 softmax-aggregate. 4 nodes per 256-thread block; one wave
// (64 threads) per node = (t,f) = (4,16). Wave-staged srcs + 2x unroll.
// ---------------------------------------------------------------------------
__global__ __launch_bounds__(256) void k_agg2(
    const float* __restrict__ feat2, const float* __restrict__ el2,
    const float* __restrict__ er2, const int* __restrict__ offs,
    const int* __restrict__ csr_src, const float* __restrict__ b2,
    float* __restrict__ out) {
  int tid = threadIdx.x;
  int n = blockIdx.x * 4 + (tid >> 6);
  int lane = tid & 63, t = lane >> 4, f = lane & 15;
  int beg = offs[n], end = offs[n + 1];
  float ern = er2[n * TT + t];
  float l = 0.f, acc = 0.f;
  for (int chunk = beg; chunk < end; chunk += 64) {
    int m = min(64, end - chunk);
    int sv = (lane < m) ? csr_src[chunk + lane] : 0;
    int j = 0;
    for (; j + 2 <= m; j += 2) {
      int s0 = __shfl(sv, j);
      int s1 = __shfl(sv, j + 1);
      float e0 = el2[s0 * TT + t];
      float e1 = el2[s1 * TT + t];
      float f0 = feat2[(s0 * TT + t) * OUT_F + f];
      float f1 = feat2[(s1 * TT + t) * OUT_F + f];
      e0 += ern; e0 = (e0 >= 0.f) ? e0 : 0.2f * e0;
      e1 += ern; e1 = (e1 >= 0.f) ? e1 : 0.2f * e1;
      float p0 = __expf(e0);
      float p1 = __expf(e1);
      l += p0 + p1;
      acc = fmaf(p0, f0, acc);
      acc = fmaf(p1, f1, acc);
    }
    if (j < m) {
      int s0 = __shfl(sv, j);
      float e0 = el2[s0 * TT + t] + ern;
      e0 = (e0 >= 0.f) ? e0 : 0.2f * e0;
      float p0 = __expf(e0);
      l += p0;
      acc = fmaf(p0, feat2[(s0 * TT + t) * OUT_F + f], acc);
    }
  }
  float r = (l > 0.f) ? (acc / l) : 0.f;
  out[(n * TT + t) * OUT_F + f] = r + b2[f];
}

// ---------------------------------------------------------------------------
extern "C" void kernel_launch(void* const* d_in, const int* in_sizes, int n_in,
                              void* d_out, int out_size, void* d_ws, size_t ws_size,
                              hipStream_t stream) {
  const float* x   = (const float*)d_in[0];
  const int*   src = (const int*)d_in[1];
  const int*   dst = (const int*)d_in[2];
  const float* W1  = (const float*)d_in[3];
  const float* al1 = (const float*)d_in[4];
  const float* ar1 = (const float*)d_in[5];
  const float* b1  = (const float*)d_in[6];
  const float* W2  = (const float*)d_in[7];
  const float* al2 = (const float*)d_in[8];
  const float* ar2 = (const float*)d_in[9];
  const float* b2  = (const float*)d_in[10];
  float* out = (float*)d_out;

  // Workspace layout (floats), ~95 MB total
  float* ws    = (float*)d_ws;
  float* feat1 = ws;                           // NT*128
  float* el1   = feat1 + (size_t)NT * C1;      // NT*8
  float* er1   = el1 + (size_t)NT * H1;        // NT*8
  float* h     = er1 + (size_t)NT * H1;        // NT*128
  float* feat2 = h + (size_t)NT * C1;          // NT*16
  float* el2   = feat2 + (size_t)NT * OUT_F;   // NT
  float* er2   = el2 + NT;                     // NT
  int* counts  = (int*)(er2 + NT);             // NN
  int* offs    = counts + NN;                  // NN+1 (pad to NN+4)
  int* cursor  = offs + NN + 4;                // NN
  int* csr_src = cursor + NN;                  // EE

  hipMemsetAsync(counts, 0, NN * sizeof(int), stream);

  k_feat1<<<NT / 16, 256, 0, stream>>>(x, W1, al1, ar1, feat1, el1, er1);
  k_count<<<EE / 256, 256, 0, stream>>>(dst, counts);
  k_scan<<<1, 1024, 0, stream>>>(counts, offs, cursor);
  k_scatter<<<EE / 256, 256, 0, stream>>>(src, dst, cursor, csr_src);
  k_agg1<<<NN, 512, 0, stream>>>(feat1, el1, er1, offs, csr_src, b1, h);
  k_feat2<<<NT / 16, 256, 0, stream>>>(h, W2, al2, ar2, feat2, el2, er2);
  k_agg2<<<NN / 4, 256, 0, stream>>>(feat2, el2, er2, offs, csr_src, b2, out);
}